// Round 7
// baseline (271.735 us; speedup 1.0000x reference)
//
#include <hip/hip_runtime.h>
#include <hip/hip_bf16.h>

// GCN encoder: 2x GCNConv (sym-norm, self-loops) + ReLU + row L2 normalize.
// N=50000, E=800000, IN=128, HID=256, OUT=256.
// MFMA bf16 GEMMs (BM=128, 8 waves, A in LDS, B streamed), bf16 gather payload.
// agg_relu: feature-split with XCD pinning (blockIdx%8 -> XCD round-robin).

#define NNODE 50000
#define FDIM 256
#define SCAN_CHUNK 2048

typedef __attribute__((ext_vector_type(8))) short short8;   // 8 bf16 (4 VGPRs)
typedef __attribute__((ext_vector_type(4))) float f32x4;    // MFMA acc / vec store

__device__ __forceinline__ float bf2f(unsigned short u) {
    union { unsigned int i; float f; } c;
    c.i = ((unsigned int)u) << 16;
    return c.f;
}
__device__ __forceinline__ unsigned short f2bf(float f) {
    __hip_bfloat16 h = __float2bfloat16(f);  // RTN
    return *reinterpret_cast<unsigned short*>(&h);
}

// ---- CSR build ----------------------------------------------------------
__global__ void count_kernel(const int* __restrict__ ei, int* __restrict__ counts, int E) {
    int e = blockIdx.x * blockDim.x + threadIdx.x;
    if (e < E) atomicAdd(&counts[ei[E + e]], 1);
}

__global__ __launch_bounds__(256) void scan_part1(const int* __restrict__ counts,
                                                  int* __restrict__ bsum, int n) {
    __shared__ int ws[4];
    int b = blockIdx.x, t = threadIdx.x;
    int base = b * SCAN_CHUNK + t * 8;
    int s = 0;
#pragma unroll
    for (int j = 0; j < 8; ++j) {
        int i = base + j;
        if (i < n) s += counts[i];
    }
#pragma unroll
    for (int off = 32; off >= 1; off >>= 1) s += __shfl_xor(s, off, 64);
    if ((t & 63) == 0) ws[t >> 6] = s;
    __syncthreads();
    if (t == 0) bsum[b] = ws[0] + ws[1] + ws[2] + ws[3];
}

__global__ void scan_part2(const int* __restrict__ bsum, int* __restrict__ boff,
                           int* __restrict__ row_ptr, int nb, int n) {
    int l = threadIdx.x;
    int v = (l < nb) ? bsum[l] : 0;
    int incl = v;
#pragma unroll
    for (int off = 1; off < 64; off <<= 1) {
        int u = __shfl_up(incl, off, 64);
        if (l >= off) incl += u;
    }
    if (l < nb) boff[l] = incl - v;
    if (l == nb - 1) row_ptr[n] = incl;  // total == E
}

// part3 also produces dinv (fused; it already has counts in registers)
__global__ __launch_bounds__(256) void scan_part3(const int* __restrict__ counts,
                                                  const int* __restrict__ boff,
                                                  int* __restrict__ row_ptr,
                                                  int* __restrict__ cursor,
                                                  float* __restrict__ dinv, int n) {
    __shared__ int ws[4];
    int b = blockIdx.x, t = threadIdx.x, lane = t & 63, wid = t >> 6;
    int base = b * SCAN_CHUNK + t * 8;
    int v[8];
    int s = 0;
#pragma unroll
    for (int j = 0; j < 8; ++j) {
        int i = base + j;
        v[j] = (i < n) ? counts[i] : 0;
        s += v[j];
    }
    int incl = s;
#pragma unroll
    for (int off = 1; off < 64; off <<= 1) {
        int u = __shfl_up(incl, off, 64);
        if (lane >= off) incl += u;
    }
    if (lane == 63) ws[wid] = incl;
    __syncthreads();
    int woff = 0;
    for (int u = 0; u < wid; ++u) woff += ws[u];
    int ex = boff[b] + woff + incl - s;
#pragma unroll
    for (int j = 0; j < 8; ++j) {
        int i = base + j;
        if (i < n) {
            row_ptr[i] = ex;
            cursor[i] = ex;
            dinv[i] = rsqrtf((float)(v[j] + 1));  // +1 self-loop
        }
        ex += v[j];
    }
}

__global__ void fill_kernel(const int* __restrict__ ei, const float* __restrict__ dinv,
                            int* __restrict__ cursor, int2* __restrict__ edata, int E) {
    int e = blockIdx.x * blockDim.x + threadIdx.x;
    if (e < E) {
        int s = ei[e];
        int d = ei[E + e];
        int pos = atomicAdd(&cursor[d], 1);
        float nm = dinv[s] * dinv[d];
        edata[pos] = make_int2(s, __float_as_int(nm));
    }
}

// ---- W repack (both layers in one launch) -------------------------------
// Wf[g][col][j] = bf16(W[8g+j][col]), fragment-ready.
__global__ void wconv_kernel(const float* __restrict__ W1, unsigned short* __restrict__ Wf1,
                             const float* __restrict__ W2, unsigned short* __restrict__ Wf2) {
    int idx = blockIdx.x * blockDim.x + threadIdx.x;
    const float* W;
    unsigned short* Wf;
    if (idx < 16 * 256) {
        W = W1; Wf = Wf1;
    } else if (idx < (16 + 32) * 256) {
        idx -= 16 * 256;
        W = W2; Wf = Wf2;
    } else {
        return;
    }
    int g = idx >> 8, c = idx & 255;
    ushort4 lo = make_ushort4(f2bf(W[(8 * g + 0) * 256 + c]), f2bf(W[(8 * g + 1) * 256 + c]),
                              f2bf(W[(8 * g + 2) * 256 + c]), f2bf(W[(8 * g + 3) * 256 + c]));
    ushort4 hi = make_ushort4(f2bf(W[(8 * g + 4) * 256 + c]), f2bf(W[(8 * g + 5) * 256 + c]),
                              f2bf(W[(8 * g + 6) * 256 + c]), f2bf(W[(8 * g + 7) * 256 + c]));
    *reinterpret_cast<ushort4*>(&Wf[(size_t)idx * 8]) = lo;
    *reinterpret_cast<ushort4*>(&Wf[(size_t)idx * 8 + 4]) = hi;
}

// ---- MFMA GEMM: H[n,256] = bf16(X[n,K] @ W[K,256]) ----------------------
// BM=128, BN=256, 512 threads = 8 waves in 2x4; wave = 64x64.
// As[row][gx][8]: gx = g ^ (row&7); B streamed from Wf via L1/L2.
template <int K, typename T>
__global__ __launch_bounds__(512, 4) void gemm_mfma(const T* __restrict__ X,
                                                    const unsigned short* __restrict__ Wf,
                                                    unsigned short* __restrict__ H, int n) {
    __shared__ unsigned short As[128 * K];
    int t = threadIdx.x;
    int row0 = blockIdx.x * 128;

    if constexpr (sizeof(T) == 4) {  // fp32 input (K=128): convert while staging
#pragma unroll
        for (int i = 0; i < (128 * K) / (4 * 512); ++i) {
            int o = 4 * (t + 512 * i);
            int row = o / K, k = o % K;
            int srow = row0 + row;
            float4 v = make_float4(0.f, 0.f, 0.f, 0.f);
            if (srow < n) v = *reinterpret_cast<const float4*>(&X[(size_t)srow * K + k]);
            ushort4 p = make_ushort4(f2bf(v.x), f2bf(v.y), f2bf(v.z), f2bf(v.w));
            int gx = (k >> 3) ^ (row & 7);
            *reinterpret_cast<ushort4*>(&As[row * K + gx * 8 + (k & 7)]) = p;
        }
    } else {  // bf16 input: straight copy
#pragma unroll
        for (int i = 0; i < (128 * K) / (8 * 512); ++i) {
            int o = 8 * (t + 512 * i);
            int row = o / K, k = o % K;
            int srow = row0 + row;
            uint4 v = make_uint4(0u, 0u, 0u, 0u);
            if (srow < n) v = *reinterpret_cast<const uint4*>(&X[(size_t)srow * K + k]);
            int gx = (k >> 3) ^ (row & 7);
            *reinterpret_cast<uint4*>(&As[row * K + gx * 8]) = v;
        }
    }
    __syncthreads();

    int lane = t & 63, wv = t >> 6;
    int rw = wv >> 2, cw = wv & 3;  // 2x4 waves
    int l15 = lane & 15, lhi = lane >> 4;
    f32x4 zero = {0.f, 0.f, 0.f, 0.f};
    f32x4 acc[4][4];
#pragma unroll
    for (int rf = 0; rf < 4; ++rf)
#pragma unroll
        for (int cf = 0; cf < 4; ++cf) acc[rf][cf] = zero;

#pragma unroll
    for (int s = 0; s < K / 32; ++s) {
        int g = 4 * s + lhi;
        short8 a[4], b[4];
#pragma unroll
        for (int rf = 0; rf < 4; ++rf) {
            int row = 64 * rw + 16 * rf + l15;
            a[rf] = *reinterpret_cast<const short8*>(&As[row * K + (g ^ (row & 7)) * 8]);
        }
#pragma unroll
        for (int cf = 0; cf < 4; ++cf) {
            int c = 64 * cw + 16 * cf + l15;
            b[cf] = *reinterpret_cast<const short8*>(&Wf[((size_t)g * 256 + c) * 8]);
        }
#pragma unroll
        for (int rf = 0; rf < 4; ++rf)
#pragma unroll
            for (int cf = 0; cf < 4; ++cf)
                acc[rf][cf] = __builtin_amdgcn_mfma_f32_16x16x32_bf16(a[rf], b[cf], acc[rf][cf], 0, 0, 0);
    }

#pragma unroll
    for (int rf = 0; rf < 4; ++rf)
#pragma unroll
        for (int cf = 0; cf < 4; ++cf) {
            f32x4 a = acc[rf][cf];
            int col = 64 * cw + 16 * cf + l15;
#pragma unroll
            for (int j = 0; j < 4; ++j) {
                int row = row0 + 64 * rw + 16 * rf + 4 * lhi + j;
                if (row < n) H[(size_t)row * 256 + col] = f2bf(a[j]);
            }
        }
}

// ---- agg_relu, feature-split + XCD-pinned. ------------------------------
// Block b: xcd = b&7 (HW round-robin); fhalf = bit2(xcd): XCD 0-3 -> feats
// [0,128), XCD 4-7 -> [128,256). Each XCD gathers from only half of h.
// Wave per node; half-wave per edge (2 edges/iter); lane owns 4 feats (8B).
__global__ __launch_bounds__(256) void agg_relu_split(const unsigned short* __restrict__ hb,
                                                      const int* __restrict__ rowp,
                                                      const int2* __restrict__ edata,
                                                      const float* __restrict__ dinv,
                                                      const float* __restrict__ bias,
                                                      unsigned short* __restrict__ outB, int n) {
    int b = blockIdx.x;
    int fhalf = (b >> 2) & 1;
    int chunk = ((b >> 3) << 2) | (b & 3);
    int node = chunk * 4 + (threadIdx.x >> 6);
    if (node >= n) return;
    int lane = threadIdx.x & 63;
    int half = lane >> 5, l31 = lane & 31;
    int fb = fhalf * 128 + l31 * 4;
    float di = dinv[node];
    float scale = half ? 0.f : 1.f;  // self+bias counted once (combined later)
    float d2 = di * di * scale;
    ushort4 sv = *reinterpret_cast<const ushort4*>(hb + (size_t)node * FDIM + fb);
    float4 bv = *reinterpret_cast<const float4*>(bias + fb);
    float a0 = fmaf(bf2f(sv.x), d2, bv.x * scale);
    float a1 = fmaf(bf2f(sv.y), d2, bv.y * scale);
    float a2 = fmaf(bf2f(sv.z), d2, bv.z * scale);
    float a3 = fmaf(bf2f(sv.w), d2, bv.w * scale);
    int beg = rowp[node], end = rowp[node + 1];
#pragma unroll 2
    for (int e = beg; e < end; e += 2) {
        int ee = e + half;
        bool valid = ee < end;
        int2 ed = edata[valid ? ee : e];
        float nm = valid ? __int_as_float(ed.y) : 0.f;
        int src = valid ? ed.x : node;
        ushort4 v = *reinterpret_cast<const ushort4*>(hb + (size_t)src * FDIM + fb);
        a0 = fmaf(bf2f(v.x), nm, a0);
        a1 = fmaf(bf2f(v.y), nm, a1);
        a2 = fmaf(bf2f(v.z), nm, a2);
        a3 = fmaf(bf2f(v.w), nm, a3);
    }
    a0 += __shfl_xor(a0, 32, 64);
    a1 += __shfl_xor(a1, 32, 64);
    a2 += __shfl_xor(a2, 32, 64);
    a3 += __shfl_xor(a3, 32, 64);
    if (half == 0) {
        ushort4 o = make_ushort4(f2bf(fmaxf(a0, 0.f)), f2bf(fmaxf(a1, 0.f)),
                                 f2bf(fmaxf(a2, 0.f)), f2bf(fmaxf(a3, 0.f)));
        *reinterpret_cast<ushort4*>(outB + (size_t)node * FDIM + fb) = o;
    }
}

// ---- agg + bias + row L2 normalize (full row; wave-per-node, 1 edge/iter)
__global__ __launch_bounds__(256) void agg_norm_kernel(const unsigned short* __restrict__ hb,
                                                       const int* __restrict__ rowp,
                                                       const int2* __restrict__ edata,
                                                       const float* __restrict__ dinv,
                                                       const float* __restrict__ bias,
                                                       float* __restrict__ out, int n) {
    int node = (blockIdx.x * blockDim.x + threadIdx.x) >> 6;
    int lane = threadIdx.x & 63;
    if (node >= n) return;
    float di = dinv[node];
    float d2 = di * di;
    ushort4 sv = *(reinterpret_cast<const ushort4*>(hb + (size_t)node * FDIM) + lane);
    float4 bv = *(reinterpret_cast<const float4*>(bias) + lane);
    float a0 = fmaf(bf2f(sv.x), d2, bv.x);
    float a1 = fmaf(bf2f(sv.y), d2, bv.y);
    float a2 = fmaf(bf2f(sv.z), d2, bv.z);
    float a3 = fmaf(bf2f(sv.w), d2, bv.w);
    int beg = rowp[node], end = rowp[node + 1];
#pragma unroll 4
    for (int e = beg; e < end; ++e) {
        int2 ed = edata[e];
        float nm = __int_as_float(ed.y);
        ushort4 v = *(reinterpret_cast<const ushort4*>(hb + (size_t)ed.x * FDIM) + lane);
        a0 = fmaf(bf2f(v.x), nm, a0);
        a1 = fmaf(bf2f(v.y), nm, a1);
        a2 = fmaf(bf2f(v.z), nm, a2);
        a3 = fmaf(bf2f(v.w), nm, a3);
    }
    float ss = a0 * a0 + a1 * a1 + a2 * a2 + a3 * a3;
#pragma unroll
    for (int off = 32; off >= 1; off >>= 1) ss += __shfl_xor(ss, off, 64);
    float rinv = 1.f / fmaxf(sqrtf(ss), 1e-12f);
    f32x4 o = {a0 * rinv, a1 * rinv, a2 * rinv, a3 * rinv};
    __builtin_nontemporal_store(o, reinterpret_cast<f32x4*>(out + (size_t)node * FDIM) + lane);
}

extern "C" void kernel_launch(void* const* d_in, const int* in_sizes, int n_in,
                              void* d_out, int out_size, void* d_ws, size_t ws_size,
                              hipStream_t stream) {
    const float* x  = (const float*)d_in[0];
    const int*   ei = (const int*)d_in[1];
    const float* W1 = (const float*)d_in[2];
    const float* b1 = (const float*)d_in[3];
    const float* W2 = (const float*)d_in[4];
    const float* b2 = (const float*)d_in[5];
    float* out = (float*)d_out;

    const int N = NNODE;
    const int E = in_sizes[1] / 2;
    const int NB = (N + SCAN_CHUNK - 1) / SCAN_CHUNK;

    char* ws = (char*)d_ws;
    size_t off = 0;
    auto alloc = [&](size_t bytes) -> void* {
        void* p = ws + off;
        off = (off + bytes + 255) & ~(size_t)255;
        return p;
    };
    unsigned short* Hbf = (unsigned short*)alloc((size_t)N * FDIM * 2);  // h1 then h2
    unsigned short* Bbf = (unsigned short*)alloc((size_t)N * FDIM * 2);  // relu(gcn1)
    unsigned short* Wf1 = (unsigned short*)alloc((size_t)(128 / 8) * 256 * 8 * 2);
    unsigned short* Wf2 = (unsigned short*)alloc((size_t)(256 / 8) * 256 * 8 * 2);
    int*   counts = (int*)alloc((size_t)N * 4);
    int*   rowp   = (int*)alloc((size_t)(N + 1) * 4);
    int*   cursor = (int*)alloc((size_t)N * 4);
    float* dinv   = (float*)alloc((size_t)N * 4);
    int2*  edata  = (int2*)alloc((size_t)E * 8);
    int*   bsum   = (int*)alloc((size_t)NB * 4);
    int*   boff   = (int*)alloc((size_t)NB * 4);

    wconv_kernel<<<(48 * 256 + 255) / 256, 256, 0, stream>>>(W1, Wf1, W2, Wf2);

    hipMemsetAsync(counts, 0, (size_t)N * 4, stream);
    count_kernel<<<(E + 255) / 256, 256, 0, stream>>>(ei, counts, E);
    scan_part1<<<NB, 256, 0, stream>>>(counts, bsum, N);
    scan_part2<<<1, 64, 0, stream>>>(bsum, boff, rowp, NB, N);
    scan_part3<<<NB, 256, 0, stream>>>(counts, boff, rowp, cursor, dinv, N);
    fill_kernel<<<(E + 255) / 256, 256, 0, stream>>>(ei, dinv, cursor, edata, E);

    gemm_mfma<128, float><<<(N + 127) / 128, 512, 0, stream>>>(x, Wf1, Hbf, N);
    int chunks = (N + 3) / 4;
    agg_relu_split<<<2 * chunks, 256, 0, stream>>>(Hbf, rowp, edata, dinv, b1, Bbf, N);
    gemm_mfma<256, unsigned short><<<(N + 127) / 128, 512, 0, stream>>>(Bbf, Wf2, Hbf, N);
    agg_norm_kernel<<<(N * 64 + 255) / 256, 256, 0, stream>>>(Hbf, rowp, edata, dinv, b2, out, N);
}